// Round 4
// baseline (264.055 us; speedup 1.0000x reference)
//
#include <hip/hip_runtime.h>

// Problem constants (reference: BATCH=8192, IN_F=2048, OUT_F=2048)
#define M_DIM 8192
#define N_DIM 2048
#define K_DIM 2048
#define LN2F 0.69314718055994530942f
#define LOG2EF 1.44269504088896340736f
#define BIAS_PHI 0.62009741f  // softplus(1) - ln2 = log((1+e)/2)

typedef _Float16 f16x8 __attribute__((ext_vector_type(8)));
typedef float f32x4 __attribute__((ext_vector_type(4)));

// ---------------------------------------------------------------------------
// softplus(x) - ln2 via native v_exp_f32 (2^x) and v_log_f32 (log2):
//   t = x*log2e;  r = (log2(1 + 2^t) - 1) * ln2
// t >= 24: 2^t dominates -> r = x - ln2. t << 0: 2^t -> 0 -> r = -ln2 (ok).
// ---------------------------------------------------------------------------
__device__ __forceinline__ float softplus_m_ln2(float v) {
    float t = v * LOG2EF;
    float e = __builtin_amdgcn_exp2f(t);
    float r = (__builtin_amdgcn_logf(1.0f + e) - 1.0f) * LN2F;
    return t < 24.0f ? r : v - LN2F;
}

// ---------------------------------------------------------------------------
// Fused prep: blocks [0, 8192) do phi; blocks [8192, 10240) do W rows.
//   phi[b,i]  = f16(softplus(x[b,i]) - ln2)          (8 elems/thread, 16B st)
//   Wh[o,i]   = f16(W[o,i]) for i<2048 (N x K row-major)
//   bias[o]   = W[o,2048] * (softplus(1)-ln2)
// ---------------------------------------------------------------------------
__global__ __launch_bounds__(256) void prep_kernel(const float* __restrict__ x,
                                                   const float* __restrict__ W,
                                                   _Float16* __restrict__ phi,
                                                   _Float16* __restrict__ Wh,
                                                   float* __restrict__ bias) {
    if (blockIdx.x < 8192) {
        size_t i = ((size_t)blockIdx.x * blockDim.x + threadIdx.x) * 8;
        float4 v0 = *(const float4*)(x + i);
        float4 v1 = *(const float4*)(x + i + 4);
        union { _Float16 h[8]; uint4 u; } pk;
        pk.h[0] = (_Float16)softplus_m_ln2(v0.x);
        pk.h[1] = (_Float16)softplus_m_ln2(v0.y);
        pk.h[2] = (_Float16)softplus_m_ln2(v0.z);
        pk.h[3] = (_Float16)softplus_m_ln2(v0.w);
        pk.h[4] = (_Float16)softplus_m_ln2(v1.x);
        pk.h[5] = (_Float16)softplus_m_ln2(v1.y);
        pk.h[6] = (_Float16)softplus_m_ln2(v1.z);
        pk.h[7] = (_Float16)softplus_m_ln2(v1.w);
        *(uint4*)(phi + i) = pk.u;
    } else {
        const int o = blockIdx.x - 8192;
        const float* row = W + (size_t)o * (K_DIM + 1) + threadIdx.x * 8;
        union { _Float16 h[8]; uint4 u; } pk;
#pragma unroll
        for (int j = 0; j < 8; ++j)
            pk.h[j] = (_Float16)row[j];
        *(uint4*)(Wh + (size_t)o * K_DIM + threadIdx.x * 8) = pk.u;
        if (threadIdx.x == 0)
            bias[o] = W[(size_t)o * (K_DIM + 1) + K_DIM] * BIAS_PHI;
    }
}

// ---------------------------------------------------------------------------
// GEMM: C[m,n] = sum_k phi[m,k] * Wh[n,k] + bias[n]
// 128x128 tile, BK=64, 4 waves in 2x2, each wave 64x64 as 4x4 of 16x16x32
// f16 MFMAs.
//
// R4 change: B (weights, 8.4 MB, L2/L3-resident) bypasses LDS — fragments
// are loaded straight global->VGPR. Each B-frag load instruction touches 16
// consecutive rows x one full 64B line -> 100% line utilization. This
// halves LDS traffic (R3 model: LDS was ~66% of the cycle budget at 96 KB
// per block-iter; now 48 KB) and the B loads are barrier-independent, so
// their latency hides under the A-DMA drain. LDS drops to 16 KB/block.
//
// A keeps the global_load_lds DMA path with the XOR swizzle: physical 16B
// chunk = logical chunk ^ (row & 7) (verified conflict-free in R2/R3).
// ---------------------------------------------------------------------------
__global__ __launch_bounds__(256) void kan_gemm(const _Float16* __restrict__ A,  // M x K
                                                const _Float16* __restrict__ B,  // N x K
                                                const float* __restrict__ bias,  // N
                                                float* __restrict__ C) {         // M x N
    __shared__ __align__(16) _Float16 sA[128 * 64];

    const int tid  = threadIdx.x;
    const int lane = tid & 63;
    const int wv   = tid >> 6;          // wave 0..3

    const size_t Arow0 = (size_t)blockIdx.x * 128;
    const size_t Brow0 = (size_t)blockIdx.y * 128;

    // A staging: one issue covers 8 rows x 64 cols. Lane l -> row l>>3,
    // physical chunk l&7, fetches logical chunk (l&7)^(l>>3 & 7).
    const int r8 = lane >> 3;
    const int lc = (lane & 7) ^ r8;
    const _Float16* gA = A + (Arow0 + wv * 32 + r8) * (size_t)K_DIM + lc * 8;
    _Float16* sAw = &sA[wv * 32 * 64];  // wave's staging region (+ j*8*64)

    // wave position within the 128x128 tile (2x2 waves of 64x64)
    const int wr = (wv >> 1) * 64;
    const int wc = (wv & 1) * 64;
    // MFMA operand addressing: outer idx = lane&15, k = (lane>>4)*8 + j.
    const int lr   = lane & 15;
    const int kph0 = ((lane >> 4) ^ (lr & 7)) * 8;  // A kc=0 elem offset (swizzled)
    // kc=1: logical chunk +4 -> physical offset XOR 32 elems

    // B row pointers: frag ni reads row (wc + ni*16 + lr), k-chunk (lane>>4)*8
    const _Float16* pB[4];
#pragma unroll
    for (int ni = 0; ni < 4; ++ni)
        pB[ni] = B + (Brow0 + wc + ni * 16 + lr) * (size_t)K_DIM + (lane >> 4) * 8;

    f32x4 acc[4][4];
#pragma unroll
    for (int i = 0; i < 4; ++i)
#pragma unroll
        for (int j = 0; j < 4; ++j)
            acc[i][j] = (f32x4){0.0f, 0.0f, 0.0f, 0.0f};

    for (int k0 = 0; k0 < K_DIM; k0 += 64) {
        // B fragments for this iter: global->VGPR, barrier-independent.
        f16x8 b0[4], b1[4];
#pragma unroll
        for (int ni = 0; ni < 4; ++ni)
            b0[ni] = *(const f16x8*)(pB[ni] + k0);

        __syncthreads();  // previous iteration's sA reads done before overwrite
#pragma unroll
        for (int j = 0; j < 4; ++j)
            __builtin_amdgcn_global_load_lds(
                (const __attribute__((address_space(1))) void*)(gA + k0 + (size_t)j * 8 * K_DIM),
                (__attribute__((address_space(3))) void*)(sAw + j * 8 * 64), 16, 0, 0);

#pragma unroll
        for (int ni = 0; ni < 4; ++ni)
            b1[ni] = *(const f16x8*)(pB[ni] + k0 + 32);

        __syncthreads();  // drains vmcnt(0): A DMA done, b0/b1 also in regs

        f16x8 af[4];
#pragma unroll
        for (int mi = 0; mi < 4; ++mi)
            af[mi] = *(const f16x8*)&sA[(wr + mi * 16 + lr) * 64 + kph0];
#pragma unroll
        for (int mi = 0; mi < 4; ++mi)
#pragma unroll
            for (int ni = 0; ni < 4; ++ni)
                acc[mi][ni] = __builtin_amdgcn_mfma_f32_16x16x32_f16(
                    af[mi], b0[ni], acc[mi][ni], 0, 0, 0);

#pragma unroll
        for (int mi = 0; mi < 4; ++mi)
            af[mi] = *(const f16x8*)&sA[(wr + mi * 16 + lr) * 64 + (kph0 ^ 32)];
#pragma unroll
        for (int mi = 0; mi < 4; ++mi)
#pragma unroll
            for (int ni = 0; ni < 4; ++ni)
                acc[mi][ni] = __builtin_amdgcn_mfma_f32_16x16x32_f16(
                    af[mi], b1[ni], acc[mi][ni], 0, 0, 0);
    }

    // Epilogue. C/D layout: col(n) = lane&15, row(m) = (lane>>4)*4 + reg.
    const int crow = (lane >> 4) * 4;
    float bsv[4];
#pragma unroll
    for (int ni = 0; ni < 4; ++ni)
        bsv[ni] = bias[Brow0 + wc + ni * 16 + lr];

#pragma unroll
    for (int mi = 0; mi < 4; ++mi) {
#pragma unroll
        for (int r = 0; r < 4; ++r) {
            float* cp = C + (Arow0 + wr + mi * 16 + crow + r) * (size_t)N_DIM
                        + Brow0 + wc + lr;
#pragma unroll
            for (int ni = 0; ni < 4; ++ni)
                cp[ni * 16] = acc[mi][ni][r] + bsv[ni];
        }
    }
}

// ---------------------------------------------------------------------------
extern "C" void kernel_launch(void* const* d_in, const int* in_sizes, int n_in,
                              void* d_out, int out_size, void* d_ws, size_t ws_size,
                              hipStream_t stream) {
    const float* x = (const float*)d_in[0];   // (8192, 2048) fp32
    const float* W = (const float*)d_in[1];   // (2048, 2049) fp32
    float* out = (float*)d_out;               // (8192, 2048) fp32

    // workspace layout: phi (M*K f16) | Wh (N*K f16) | bias (N f32)  ~42 MB
    char* ws = (char*)d_ws;
    _Float16* phi = (_Float16*)ws;
    _Float16* Wh  = (_Float16*)(ws + (size_t)M_DIM * K_DIM * sizeof(_Float16));
    float* bias   = (float*)(ws + (size_t)M_DIM * K_DIM * sizeof(_Float16)
                                + (size_t)N_DIM * K_DIM * sizeof(_Float16));

    prep_kernel<<<8192 + 2048, 256, 0, stream>>>(x, W, phi, Wh, bias);
    dim3 grid(M_DIM / 128, N_DIM / 128);  // 64 x 16 = 1024 blocks
    kan_gemm<<<grid, 256, 0, stream>>>(phi, Wh, bias, out);
}

// Round 5
// 185.045 us; speedup vs baseline: 1.4270x; 1.4270x over previous
//
#include <hip/hip_runtime.h>

// Problem constants (reference: BATCH=8192, IN_F=2048, OUT_F=2048)
#define M_DIM 8192
#define N_DIM 2048
#define K_DIM 2048
#define LN2F 0.69314718055994530942f
#define LOG2EF 1.44269504088896340736f
#define BIAS_PHI 0.62009741f  // softplus(1) - ln2 = log((1+e)/2)

typedef _Float16 f16x8 __attribute__((ext_vector_type(8)));
typedef float f32x4 __attribute__((ext_vector_type(4)));

// ---------------------------------------------------------------------------
// softplus(x) - ln2 via native v_exp_f32 (2^x) and v_log_f32 (log2):
//   t = x*log2e;  r = (log2(1 + 2^t) - 1) * ln2
// t >= 24: 2^t dominates -> r = x - ln2. t << 0: 2^t -> 0 -> r = -ln2 (ok).
// ---------------------------------------------------------------------------
__device__ __forceinline__ float softplus_m_ln2(float v) {
    float t = v * LOG2EF;
    float e = __builtin_amdgcn_exp2f(t);
    float r = (__builtin_amdgcn_logf(1.0f + e) - 1.0f) * LN2F;
    return t < 24.0f ? r : v - LN2F;
}

// ---------------------------------------------------------------------------
// Fused prep: blocks [0, 8192) do phi; blocks [8192, 10240) do W rows.
//   phi[b,i]  = f16(softplus(x[b,i]) - ln2)          (8 elems/thread, 16B st)
//   Wh[o,i]   = f16(W[o,i]) for i<2048 (N x K row-major)
//   bias[o]   = W[o,2048] * (softplus(1)-ln2)
// ---------------------------------------------------------------------------
__global__ __launch_bounds__(256) void prep_kernel(const float* __restrict__ x,
                                                   const float* __restrict__ W,
                                                   _Float16* __restrict__ phi,
                                                   _Float16* __restrict__ Wh,
                                                   float* __restrict__ bias) {
    if (blockIdx.x < 8192) {
        size_t i = ((size_t)blockIdx.x * blockDim.x + threadIdx.x) * 8;
        float4 v0 = *(const float4*)(x + i);
        float4 v1 = *(const float4*)(x + i + 4);
        union { _Float16 h[8]; uint4 u; } pk;
        pk.h[0] = (_Float16)softplus_m_ln2(v0.x);
        pk.h[1] = (_Float16)softplus_m_ln2(v0.y);
        pk.h[2] = (_Float16)softplus_m_ln2(v0.z);
        pk.h[3] = (_Float16)softplus_m_ln2(v0.w);
        pk.h[4] = (_Float16)softplus_m_ln2(v1.x);
        pk.h[5] = (_Float16)softplus_m_ln2(v1.y);
        pk.h[6] = (_Float16)softplus_m_ln2(v1.z);
        pk.h[7] = (_Float16)softplus_m_ln2(v1.w);
        *(uint4*)(phi + i) = pk.u;
    } else {
        const int o = blockIdx.x - 8192;
        const float* row = W + (size_t)o * (K_DIM + 1) + threadIdx.x * 8;
        union { _Float16 h[8]; uint4 u; } pk;
#pragma unroll
        for (int j = 0; j < 8; ++j)
            pk.h[j] = (_Float16)row[j];
        *(uint4*)(Wh + (size_t)o * K_DIM + threadIdx.x * 8) = pk.u;
        if (threadIdx.x == 0)
            bias[o] = W[(size_t)o * (K_DIM + 1) + K_DIM] * BIAS_PHI;
    }
}

// ---------------------------------------------------------------------------
// GEMM: C[m,n] = sum_k phi[m,k] * Wh[n,k] + bias[n]
//
// R5: both operands back through the LDS DMA path (R4 showed scattered
// global B-loads cost ~16 cache lines per instr -> 2x regression).
// LDS-bandwidth model of R3 (67% of cycles) says the lever is WAVE-tile
// size: 128x64 per wave reads 24 KB LDS per K64-iter for 512K MACs vs
// 64x64's 16 KB per 256K MACs -> 0.75x LDS bytes/FLOP.
//
// Block tile 256x128, 4 waves in 2x2 (each wave 128 rows x 64 cols),
// BK=64, acc[8][4] (128 VGPRs). LDS = 48 KB. Grid 32x16 = 512 blocks
// = exactly 2 blocks/CU.
//
// XOR swizzle (verified conflict-free R2/R3): row = 64 f16 = 8 chunks of
// 16 B; physical chunk = logical chunk ^ (row & 7). DMA keeps the fixed
// lane -> base+lane*16 layout; lanes fetch the permuted global chunk
// (same 128 B row segment -> coalescing unchanged).
// ---------------------------------------------------------------------------
__global__ __launch_bounds__(256, 2) void kan_gemm(const _Float16* __restrict__ A,  // M x K
                                                   const _Float16* __restrict__ B,  // N x K
                                                   const float* __restrict__ bias,  // N
                                                   float* __restrict__ C) {         // M x N
    __shared__ __align__(16) _Float16 sA[256 * 64];  // 32 KB
    __shared__ __align__(16) _Float16 sB[128 * 64];  // 16 KB

    const int tid  = threadIdx.x;
    const int lane = tid & 63;
    const int wv   = tid >> 6;          // wave 0..3

    const size_t Arow0 = (size_t)blockIdx.x * 256;
    const size_t Brow0 = (size_t)blockIdx.y * 128;

    // Staging: one issue covers 8 rows x 64 cols. Lane l -> row l>>3,
    // physical chunk l&7, fetches logical chunk (l&7)^(l>>3).
    const int r8 = lane >> 3;
    const int lc = (lane & 7) ^ r8;

    // A: wave wv stages rows [wv*64, wv*64+64) in 8 issues of 8 rows.
    const _Float16* gA = A + (Arow0 + wv * 64 + r8) * (size_t)K_DIM + lc * 8;
    _Float16* sAw = &sA[wv * 64 * 64];
    // B: wave wv stages rows [wv*32, wv*32+32) in 4 issues of 8 rows.
    const _Float16* gB = B + (Brow0 + wv * 32 + r8) * (size_t)K_DIM + lc * 8;
    _Float16* sBw = &sB[wv * 32 * 64];

    // wave position: 2x2 grid of 128x64 patches
    const int wr = (wv >> 1) * 128;
    const int wc = (wv & 1) * 64;
    // MFMA operand addressing: outer idx = lane&15, logical chunk
    // c = (lane>>4) + 4*kc; physical = c ^ (lr & 7); kc=1 -> XOR 32 elems.
    const int lr   = lane & 15;
    const int kph0 = ((lane >> 4) ^ (lr & 7)) * 8;

    f32x4 acc[8][4];
#pragma unroll
    for (int i = 0; i < 8; ++i)
#pragma unroll
        for (int j = 0; j < 4; ++j)
            acc[i][j] = (f32x4){0.0f, 0.0f, 0.0f, 0.0f};

    for (int k0 = 0; k0 < K_DIM; k0 += 64) {
        __syncthreads();  // previous iteration's ds_reads done before overwrite
#pragma unroll
        for (int j = 0; j < 8; ++j)
            __builtin_amdgcn_global_load_lds(
                (const __attribute__((address_space(1))) void*)(gA + k0 + (size_t)j * 8 * K_DIM),
                (__attribute__((address_space(3))) void*)(sAw + j * 8 * 64), 16, 0, 0);
#pragma unroll
        for (int j = 0; j < 4; ++j)
            __builtin_amdgcn_global_load_lds(
                (const __attribute__((address_space(1))) void*)(gB + k0 + (size_t)j * 8 * K_DIM),
                (__attribute__((address_space(3))) void*)(sBw + j * 8 * 64), 16, 0, 0);
        __syncthreads();  // drains vmcnt(0): staging complete

#pragma unroll
        for (int kc = 0; kc < 2; ++kc) {
            const int ko = kph0 ^ (kc * 32);
            f16x8 bfr[4];
#pragma unroll
            for (int ni = 0; ni < 4; ++ni)
                bfr[ni] = *(const f16x8*)&sB[(wc + ni * 16 + lr) * 64 + ko];

#pragma unroll
            for (int mh = 0; mh < 2; ++mh) {
                f16x8 af[4];
#pragma unroll
                for (int mi = 0; mi < 4; ++mi)
                    af[mi] = *(const f16x8*)&sA[(wr + (mh * 4 + mi) * 16 + lr) * 64 + ko];
#pragma unroll
                for (int mi = 0; mi < 4; ++mi)
#pragma unroll
                    for (int ni = 0; ni < 4; ++ni)
                        acc[mh * 4 + mi][ni] = __builtin_amdgcn_mfma_f32_16x16x32_f16(
                            af[mi], bfr[ni], acc[mh * 4 + mi][ni], 0, 0, 0);
            }
        }
    }

    // Epilogue. C/D layout: col(n) = lane&15, row(m) = (lane>>4)*4 + reg.
    const int crow = (lane >> 4) * 4;
    float bsv[4];
#pragma unroll
    for (int ni = 0; ni < 4; ++ni)
        bsv[ni] = bias[Brow0 + wc + ni * 16 + lr];

#pragma unroll
    for (int mi = 0; mi < 8; ++mi) {
#pragma unroll
        for (int r = 0; r < 4; ++r) {
            float* cp = C + (Arow0 + wr + mi * 16 + crow + r) * (size_t)N_DIM
                        + Brow0 + wc + lr;
#pragma unroll
            for (int ni = 0; ni < 4; ++ni)
                cp[ni * 16] = acc[mi][ni][r] + bsv[ni];
        }
    }
}

// ---------------------------------------------------------------------------
extern "C" void kernel_launch(void* const* d_in, const int* in_sizes, int n_in,
                              void* d_out, int out_size, void* d_ws, size_t ws_size,
                              hipStream_t stream) {
    const float* x = (const float*)d_in[0];   // (8192, 2048) fp32
    const float* W = (const float*)d_in[1];   // (2048, 2049) fp32
    float* out = (float*)d_out;               // (8192, 2048) fp32

    // workspace layout: phi (M*K f16) | Wh (N*K f16) | bias (N f32)  ~42 MB
    char* ws = (char*)d_ws;
    _Float16* phi = (_Float16*)ws;
    _Float16* Wh  = (_Float16*)(ws + (size_t)M_DIM * K_DIM * sizeof(_Float16));
    float* bias   = (float*)(ws + (size_t)M_DIM * K_DIM * sizeof(_Float16)
                                + (size_t)N_DIM * K_DIM * sizeof(_Float16));

    prep_kernel<<<8192 + 2048, 256, 0, stream>>>(x, W, phi, Wh, bias);
    dim3 grid(M_DIM / 256, N_DIM / 128);  // 32 x 16 = 512 blocks, 2/CU
    kan_gemm<<<grid, 256, 0, stream>>>(phi, Wh, bias, out);
}